// Round 1
// baseline (252.437 us; speedup 1.0000x reference)
//
#include <hip/hip_runtime.h>
#include <math.h>

constexpr int B = 4, T = 2048, C = 1024, H = 16, D = 64;
constexpr int M = B * T;
constexpr size_t BTC = (size_t)B * T * C;
constexpr float QSCALE = 0.18033688011112042f;   // 0.125 * log2(e)
constexpr float ROPE_C = -0.415241011861f;       // -log2(10000)/32

typedef short bf16x8 __attribute__((ext_vector_type(8)));
typedef float f32x4 __attribute__((ext_vector_type(4)));

__device__ inline ushort f2bf(float f) {
  union { float f; unsigned u; } cv; cv.f = f;
  unsigned u = cv.u;
  u += 0x7fffu + ((u >> 16) & 1u);   // round-to-nearest-even
  return (ushort)(u >> 16);
}
__device__ inline ushort f2bfr(float f) {  // fast round (P only)
  union { float f; unsigned u; } cv; cv.f = f;
  return (ushort)((cv.u + 0x8000u) >> 16);
}

__device__ inline void async_load16(const void* g, void* l) {
  __builtin_amdgcn_global_load_lds(
      (const __attribute__((address_space(1))) void*)g,
      (__attribute__((address_space(3))) void*)l, 16, 0, 0);
}

__device__ __forceinline__ bf16x8 ones_frag() {
  bf16x8 v;
#pragma unroll
  for (int i = 0; i < 8; i++) v[i] = (short)0x3F80;  // bf16 1.0
  return v;
}

// ---------------------------------------------------------------------------
// fp32 -> bf16 conversion, 4 elems/thread
// ---------------------------------------------------------------------------
__global__ __launch_bounds__(256) void f32_to_bf16(
    const float* __restrict__ in, ushort* __restrict__ outp) {
  int i = (blockIdx.x * 256 + threadIdx.x) * 4;
  float4 v = *(const float4*)(in + i);
  ushort4 o;
  o.x = f2bf(v.x); o.y = f2bf(v.y); o.z = f2bf(v.z); o.w = f2bf(v.w);
  *(ushort4*)(outp + i) = o;
}

// Convert 4 weight matrices (C*C each) into contiguous dst in one launch.
__global__ __launch_bounds__(256) void conv_weights(
    const float* __restrict__ w0, const float* __restrict__ w1,
    const float* __restrict__ w2, const float* __restrict__ w3,
    ushort* __restrict__ outp) {
  const int seg_blocks = (C * C) / 1024;
  int seg = blockIdx.x / seg_blocks;
  int blk = blockIdx.x - seg * seg_blocks;
  const float* src = (seg == 0) ? w0 : (seg == 1) ? w1 : (seg == 2) ? w2 : w3;
  int i = (blk * 256 + threadIdx.x) * 4;
  float4 v = *(const float4*)(src + i);
  ushort4 o;
  o.x = f2bf(v.x); o.y = f2bf(v.y); o.z = f2bf(v.z); o.w = f2bf(v.w);
  *(ushort4*)(outp + (size_t)seg * C * C + i) = o;
}

// ---------------------------------------------------------------------------
// 256x256 / BK=64 8-phase QKV GEMM (T2 swizzle + T3/T4 counted vmcnt + T5
// setprio), fused RoPE + V-transpose epilogue.
// 512 thr = 8 waves (2M x 4N); per-wave 128x64 output; LDS 128 KiB dbuf.
// Steady state: one s_waitcnt vmcnt(4) per K-tile (A-panel of t+2 stays in
// flight across the barrier); B(t+1) issued at phase 0, A(t+2) at phase 3
// (that buffer's reads are all done by the phase-2 end barrier).
// ---------------------------------------------------------------------------
constexpr int QNT = C / 64;  // 16 K-tiles

__global__ __launch_bounds__(512, 2) void gemm256_qkv(
    const ushort* __restrict__ A, const ushort* __restrict__ Wt,
    const float* __restrict__ b0, const float* __restrict__ b1,
    const float* __restrict__ b2, ushort* __restrict__ outq,
    ushort* __restrict__ outk, ushort* __restrict__ outv) {
  __shared__ ushort As[2][256 * 64] __attribute__((aligned(16)));
  __shared__ ushort Bs[2][256 * 64] __attribute__((aligned(16)));
  const int tid = threadIdx.x;
  const int lane = tid & 63;
  const int lrow = lane & 15, quad = lane >> 4;
  const int wave = tid >> 6;
  const int wr = wave >> 2, wc = wave & 3;   // 2 x 4 wave grid

  // XCD-aware bijective swizzle: 384 blocks = 8 XCDs x 48 contiguous tiles.
  int bid = blockIdx.y * 12 + blockIdx.x;
  int lin = (bid & 7) * 48 + (bid >> 3);
  int row0 = (lin / 12) * 256;
  int col0 = (lin % 12) * 256;

  // Per-thread staging addresses (source col-chunk XOR-swizzled so the
  // linear global_load_lds destination yields a swizzled LDS tile).
  unsigned ga[4], gb[4];
#pragma unroll
  for (int i = 0; i < 4; i++) {
    int c = tid + i * 512;
    int r = c >> 3, cl = c & 7;
    int g = (cl ^ (r & 7)) * 8;
    ga[i] = (unsigned)(row0 + r) * C + g;
    gb[i] = (unsigned)(col0 + r) * C + g;
  }

  f32x4 acc[8][4];
#pragma unroll
  for (int i = 0; i < 8; i++)
#pragma unroll
    for (int j = 0; j < 4; j++) acc[i][j] = (f32x4){0.f, 0.f, 0.f, 0.f};

  const int x7 = lrow & 7;
  const int sl0 = ((0 * 4 + quad) ^ x7) * 8;   // k-half 0 chunk (elems)
  const int sl1 = ((1 * 4 + quad) ^ x7) * 8;   // k-half 1 chunk

  // ---- prologue: issue A(0), B(0), A(1); wait leaving A(1) in flight ----
#pragma unroll
  for (int i = 0; i < 4; i++)
    async_load16(A + ga[i], &As[0][(tid + i * 512) * 8]);
#pragma unroll
  for (int i = 0; i < 4; i++)
    async_load16(Wt + gb[i], &Bs[0][(tid + i * 512) * 8]);
#pragma unroll
  for (int i = 0; i < 4; i++)
    async_load16(A + ga[i] + 64, &As[1][(tid + i * 512) * 8]);
  asm volatile("s_waitcnt vmcnt(4)" ::: "memory");
  __builtin_amdgcn_sched_barrier(0);
  __builtin_amdgcn_s_barrier();

  for (int t = 0; t < QNT; ++t) {
    const int p = t & 1;
    const ushort* Ap = As[p];
    const ushort* Bp = Bs[p];
    ushort* Bnext = Bs[p ^ 1];

    // ---- phase 0: read A(mh=0) + B(nh=0) frags; prefetch B(t+1) ----
    bf16x8 af[4][2], bf0[2][2];
#pragma unroll
    for (int mf = 0; mf < 4; mf++) {
      const ushort* rp = &Ap[(wr * 128 + mf * 16 + lrow) * 64];
      af[mf][0] = *(const bf16x8*)(rp + sl0);
      af[mf][1] = *(const bf16x8*)(rp + sl1);
    }
#pragma unroll
    for (int nf = 0; nf < 2; nf++) {
      const ushort* rp = &Bp[(wc * 64 + nf * 16 + lrow) * 64];
      bf0[nf][0] = *(const bf16x8*)(rp + sl0);
      bf0[nf][1] = *(const bf16x8*)(rp + sl1);
    }
    if (t + 1 < QNT) {
#pragma unroll
      for (int i = 0; i < 4; i++)
        async_load16(Wt + gb[i] + (t + 1) * 64, &Bnext[(tid + i * 512) * 8]);
    }
    __builtin_amdgcn_s_barrier();
    __builtin_amdgcn_s_setprio(1);
#pragma unroll
    for (int mf = 0; mf < 4; mf++)
#pragma unroll
      for (int nf = 0; nf < 2; nf++) {
        acc[mf][nf] = __builtin_amdgcn_mfma_f32_16x16x32_bf16(
            af[mf][0], bf0[nf][0], acc[mf][nf], 0, 0, 0);
        acc[mf][nf] = __builtin_amdgcn_mfma_f32_16x16x32_bf16(
            af[mf][1], bf0[nf][1], acc[mf][nf], 0, 0, 0);
      }
    __builtin_amdgcn_s_setprio(0);
    __builtin_amdgcn_s_barrier();

    // ---- phase 1: read B(nh=1) frags; MFMA A0 x B1 ----
    bf16x8 bf1[2][2];
#pragma unroll
    for (int nf = 0; nf < 2; nf++) {
      const ushort* rp = &Bp[(wc * 64 + (2 + nf) * 16 + lrow) * 64];
      bf1[nf][0] = *(const bf16x8*)(rp + sl0);
      bf1[nf][1] = *(const bf16x8*)(rp + sl1);
    }
    __builtin_amdgcn_s_barrier();
    __builtin_amdgcn_s_setprio(1);
#pragma unroll
    for (int mf = 0; mf < 4; mf++)
#pragma unroll
      for (int nf = 0; nf < 2; nf++) {
        acc[mf][2 + nf] = __builtin_amdgcn_mfma_f32_16x16x32_bf16(
            af[mf][0], bf1[nf][0], acc[mf][2 + nf], 0, 0, 0);
        acc[mf][2 + nf] = __builtin_amdgcn_mfma_f32_16x16x32_bf16(
            af[mf][1], bf1[nf][1], acc[mf][2 + nf], 0, 0, 0);
      }
    __builtin_amdgcn_s_setprio(0);
    __builtin_amdgcn_s_barrier();

    // ---- phase 2: read A(mh=1) frags; MFMA A1 x B1 ----
    bf16x8 af2[4][2];
#pragma unroll
    for (int mf = 0; mf < 4; mf++) {
      const ushort* rp = &Ap[(wr * 128 + 64 + mf * 16 + lrow) * 64];
      af2[mf][0] = *(const bf16x8*)(rp + sl0);
      af2[mf][1] = *(const bf16x8*)(rp + sl1);
    }
    __builtin_amdgcn_s_barrier();
    __builtin_amdgcn_s_setprio(1);
#pragma unroll
    for (int mf = 0; mf < 4; mf++)
#pragma unroll
      for (int nf = 0; nf < 2; nf++) {
        acc[4 + mf][2 + nf] = __builtin_amdgcn_mfma_f32_16x16x32_bf16(
            af2[mf][0], bf1[nf][0], acc[4 + mf][2 + nf], 0, 0, 0);
        acc[4 + mf][2 + nf] = __builtin_amdgcn_mfma_f32_16x16x32_bf16(
            af2[mf][1], bf1[nf][1], acc[4 + mf][2 + nf], 0, 0, 0);
      }
    __builtin_amdgcn_s_setprio(0);
    __builtin_amdgcn_s_barrier();

    // ---- phase 3: prefetch A(t+2) into buf p (its reads finished at the
    //      phase-2 barrier); counted wait: tile t+1 done, A(t+2) in flight ----
    if (t + 2 < QNT) {
#pragma unroll
      for (int i = 0; i < 4; i++)
        async_load16(A + ga[i] + (t + 2) * 64, &As[p][(tid + i * 512) * 8]);
      asm volatile("s_waitcnt vmcnt(4)" ::: "memory");
    } else {
      asm volatile("s_waitcnt vmcnt(0)" ::: "memory");
    }
    __builtin_amdgcn_sched_barrier(0);
    __builtin_amdgcn_s_barrier();
    __builtin_amdgcn_s_setprio(1);
#pragma unroll
    for (int mf = 0; mf < 4; mf++)
#pragma unroll
      for (int nf = 0; nf < 2; nf++) {
        acc[4 + mf][nf] = __builtin_amdgcn_mfma_f32_16x16x32_bf16(
            af2[mf][0], bf0[nf][0], acc[4 + mf][nf], 0, 0, 0);
        acc[4 + mf][nf] = __builtin_amdgcn_mfma_f32_16x16x32_bf16(
            af2[mf][1], bf0[nf][1], acc[4 + mf][nf], 0, 0, 0);
      }
    __builtin_amdgcn_s_setprio(0);
    __builtin_amdgcn_s_barrier();
  }

  // ---- fused epilogue (identical math to the proven 128^2 version) ----
  const int nb = col0 + wc * 64;             // head-aligned
  const int mbase = row0 + wr * 128;
  const float* bias = (col0 < 1024) ? b0 : (col0 < 2048) ? b1 : b2;
  float bn[4];
#pragma unroll
  for (int j = 0; j < 4; j++) bn[j] = bias[(nb & 1023) + j * 16 + lrow];

  int seg = nb >> 10;                        // 0=Q, 1=K, 2=V
  int hh = (nb & 1023) >> 6;                 // head index
  if (seg < 2) {
    // RoPE: lane holds d = lrow(+16) and d+32 -> both pair halves local.
    ushort* dst = (seg == 0) ? outq : outk;
    float scale = (seg == 0) ? QSCALE : 1.0f;
    float a0 = __builtin_amdgcn_exp2f((float)lrow * ROPE_C);
    float a1 = __builtin_amdgcn_exp2f((float)(lrow + 16) * ROPE_C);
#pragma unroll
    for (int mf = 0; mf < 8; mf++) {
#pragma unroll
      for (int r = 0; r < 4; r++) {
        int m = mbase + mf * 16 + quad * 4 + r;
        int tt = m & (T - 1), bb = m >> 11;
        float s0, c0, s1, c1;
        __sincosf((float)tt * a0, &s0, &c0);
        __sincosf((float)tt * a1, &s1, &c1);
        float xr0 = acc[mf][0][r] + bn[0];
        float xi0 = acc[mf][2][r] + bn[2];
        float xr1 = acc[mf][1][r] + bn[1];
        float xi1 = acc[mf][3][r] + bn[3];
        ushort* pp = dst + ((size_t)(bb * H + hh) * T + tt) * D + lrow;
        pp[0]  = f2bf((xr0 * c0 - xi0 * s0) * scale);
        pp[32] = f2bf((xr0 * s0 + xi0 * c0) * scale);
        pp[16] = f2bf((xr1 * c1 - xi1 * s1) * scale);
        pp[48] = f2bf((xr1 * s1 + xi1 * c1) * scale);
      }
    }
  } else {
    // V: write transposed (B,H,D,T); 4 consecutive t per quad -> ushort4
#pragma unroll
    for (int mf = 0; mf < 8; mf++) {
      int m0 = mbase + mf * 16 + quad * 4;
      int t0 = m0 & (T - 1), bb = m0 >> 11;
      size_t base = (size_t)(bb * H + hh) * D * T + t0;
#pragma unroll
      for (int j = 0; j < 4; j++) {
        int d = j * 16 + lrow;
        ushort4 pk;
        pk.x = f2bf(acc[mf][j][0] + bn[j]);
        pk.y = f2bf(acc[mf][j][1] + bn[j]);
        pk.z = f2bf(acc[mf][j][2] + bn[j]);
        pk.w = f2bf(acc[mf][j][3] + bn[j]);
        *(ushort4*)(outv + base + (size_t)d * T) = pk;
      }
    }
  }
}

// ---------------------------------------------------------------------------
// MFMA GEMM: 128x128 tile, BK=64 (kept for the proj GEMM, OM=0 only).
// ---------------------------------------------------------------------------
#define GT 128
#define GBK 64
template <int OM>
__global__ __launch_bounds__(256) void gemm_mfma_bt(
    const ushort* __restrict__ A, const ushort* __restrict__ Wt,
    const float* __restrict__ b0, const float* __restrict__ b1,
    const float* __restrict__ b2, void* __restrict__ out1,
    void* __restrict__ out2, void* __restrict__ out3,
    int N, int K) {
  __shared__ ushort As[GT * GBK] __attribute__((aligned(16)));
  __shared__ ushort Bs[GT * GBK] __attribute__((aligned(16)));
  int tid = threadIdx.x;
  int lane = tid & 63;
  int lrow = lane & 15, quad = lane >> 4;
  int wave = tid >> 6;
  int wr = wave >> 1, wc = wave & 1;
  int row0 = blockIdx.y * GT;
  int col0 = blockIdx.x * GT;
  const float* bias = (col0 < 1024) ? b0 : (col0 < 2048) ? b1 : b2;

  size_t ga[4], gb[4];
#pragma unroll
  for (int i = 0; i < 4; i++) {
    int cc = tid + i * 256;
    int r = cc >> 3, cl = cc & 7;
    int g = (cl ^ (r & 7)) * 8;        // XOR-swizzled source col-chunk
    ga[i] = (size_t)(row0 + r) * K + g;
    gb[i] = (size_t)(col0 + r) * K + g;
  }
  int x7 = lrow & 7;

  f32x4 acc[4][4];
#pragma unroll
  for (int i = 0; i < 4; i++)
#pragma unroll
    for (int j = 0; j < 4; j++) acc[i][j] = (f32x4){0.f, 0.f, 0.f, 0.f};

  for (int k0 = 0; k0 < K; k0 += GBK) {
#pragma unroll
    for (int i = 0; i < 4; i++) {
      int cc = tid + i * 256;
      async_load16(A + ga[i] + k0, &As[cc * 8]);
      async_load16(Wt + gb[i] + k0, &Bs[cc * 8]);
    }
    __syncthreads();
#pragma unroll
    for (int kh = 0; kh < 2; kh++) {
      int slot = ((kh * 4 + quad) ^ x7) * 8;
      bf16x8 af[4], bfr[4];
#pragma unroll
      for (int i = 0; i < 4; i++)
        af[i] = *(const bf16x8*)&As[(wr * 64 + i * 16 + lrow) * GBK + slot];
#pragma unroll
      for (int j = 0; j < 4; j++)
        bfr[j] = *(const bf16x8*)&Bs[(wc * 64 + j * 16 + lrow) * GBK + slot];
#pragma unroll
      for (int i = 0; i < 4; i++)
#pragma unroll
        for (int j = 0; j < 4; j++)
          acc[i][j] = __builtin_amdgcn_mfma_f32_16x16x32_bf16(af[i], bfr[j], acc[i][j], 0, 0, 0);
    }
    __syncthreads();
  }

  int nb = col0 + wc * 64;             // head-aligned (64 | nb)
  int mbase = row0 + wr * 64;
  float bn[4];
#pragma unroll
  for (int j = 0; j < 4; j++) bn[j] = bias[(nb & 1023) + j * 16 + lrow];

  if (OM == 0) {
    float* outp = (float*)out1;
#pragma unroll
    for (int i = 0; i < 4; i++)
#pragma unroll
      for (int j = 0; j < 4; j++) {
        int n = nb + j * 16 + lrow;
#pragma unroll
        for (int r = 0; r < 4; r++) {
          int m = mbase + i * 16 + quad * 4 + r;
          outp[(size_t)m * N + n] = acc[i][j][r] + bn[j];
        }
      }
  }
}

// ---------------------------------------------------------------------------
// MFMA flash attention v4 (unchanged).
// ---------------------------------------------------------------------------
__device__ __forceinline__ void stage_kv(
    const ushort* kbh, const ushort* vbh, int s0,
    ushort* Kl, ushort* Vl, int tid) {
#pragma unroll
  for (int i = 0; i < 2; i++) {
    int c = tid + i * 256;
    int r = c >> 3, cc = c & 7;
    int g = (cc ^ (r & 7)) * 8;
    async_load16(kbh + (size_t)(s0 + r) * D + g, Kl + c * 8);
    async_load16(vbh + (size_t)r * T + s0 + g, Vl + c * 8);
  }
}

template <int MODE>
__device__ __forceinline__ void attn_step4(
    int s0, const ushort* KL, const ushort* VL, ushort* P,
    const bf16x8 (&qf)[2][2], int lrow, int quad, int sw0, int sw1,
    int qg0, int qg1, f32x4 (&o)[4][2], f32x4 (&ol)[2]) {
  bf16x8 kf0[4], kf1[4];
#pragma unroll
  for (int kt = 0; kt < 4; kt++) {
    int base = (kt * 16 + lrow) * 64;
    kf0[kt] = *(const bf16x8*)&KL[base + sw0];
    kf1[kt] = *(const bf16x8*)&KL[base + sw1];
  }
  bf16x8 vf0[4], vf1[4];
#pragma unroll
  for (int ds = 0; ds < 4; ds++) {
    int base = (ds * 16 + lrow) * 64;
    vf0[ds] = *(const bf16x8*)&VL[base + sw0];
    vf1[ds] = *(const bf16x8*)&VL[base + sw1];
  }
#pragma unroll
  for (int g = 0; g < 2; g++) {
    if (MODE == 2 && g == 0) continue;
    int qg = g ? qg1 : qg0;
    f32x4 st[4];
#pragma unroll
    for (int kt = 0; kt < 4; kt++) {
      f32x4 z = {0.f, 0.f, 0.f, 0.f};
      st[kt] = __builtin_amdgcn_mfma_f32_16x16x32_bf16(kf0[kt], qf[g][0], z, 0, 0, 0);
      st[kt] = __builtin_amdgcn_mfma_f32_16x16x32_bf16(kf1[kt], qf[g][1], st[kt], 0, 0, 0);
    }
    if ((MODE == 1 && g == 0) || (MODE == 2 && g == 1)) {
#pragma unroll
      for (int kt = 0; kt < 4; kt++)
#pragma unroll
        for (int r = 0; r < 4; r++)
          if (s0 + kt * 16 + quad * 4 + r > qg) st[kt][r] = -1e30f;
    }
#pragma unroll
    for (int kt = 0; kt < 4; kt++) {
      ushort4 pk;
      pk.x = f2bfr(__builtin_amdgcn_exp2f(st[kt][0]));
      pk.y = f2bfr(__builtin_amdgcn_exp2f(st[kt][1]));
      pk.z = f2bfr(__builtin_amdgcn_exp2f(st[kt][2]));
      pk.w = f2bfr(__builtin_amdgcn_exp2f(st[kt][3]));
      *(ushort4*)&P[((2 * kt + (quad >> 1)) * 32 + g * 16 + lrow) * 8 + (quad & 1) * 4] = pk;
    }
  }
  asm volatile("" ::: "memory");
  bf16x8 ones = ones_frag();
#pragma unroll
  for (int g = 0; g < 2; g++) {
    if (MODE == 2 && g == 0) continue;
    bf16x8 pf0 = *(const bf16x8*)&P[(quad * 32 + g * 16 + lrow) * 8];
    bf16x8 pf1 = *(const bf16x8*)&P[((quad + 4) * 32 + g * 16 + lrow) * 8];
    ol[g] = __builtin_amdgcn_mfma_f32_16x16x32_bf16(ones, pf0, ol[g], 0, 0, 0);
    ol[g] = __builtin_amdgcn_mfma_f32_16x16x32_bf16(ones, pf1, ol[g], 0, 0, 0);
#pragma unroll
    for (int ds = 0; ds < 4; ds++) {
      o[ds][g] = __builtin_amdgcn_mfma_f32_16x16x32_bf16(vf0[ds], pf0, o[ds][g], 0, 0, 0);
      o[ds][g] = __builtin_amdgcn_mfma_f32_16x16x32_bf16(vf1[ds], pf1, o[ds][g], 0, 0, 0);
    }
  }
}

__global__ __launch_bounds__(256, 3) void attn_mfma4(
    const ushort* __restrict__ qb_, const ushort* __restrict__ kb_,
    const ushort* __restrict__ vtb_, ushort* __restrict__ y) {
  __shared__ ushort Kl[2][64 * 64] __attribute__((aligned(16)));
  __shared__ ushort Vl[2][64 * 64] __attribute__((aligned(16)));
  __shared__ ushort Pl[4][2048] __attribute__((aligned(16)));
  int tid = threadIdx.x;
  int wave = tid >> 6, lane = tid & 63;
  int lrow = lane & 15, quad = lane >> 4;
  int qbi = 15 - (int)(blockIdx.x >> 6);
  int bh = blockIdx.x & 63;
  int b = bh >> 4, h = bh & 15;
  int Q0 = qbi * 128;
  ushort* P = Pl[wave];
  const ushort* kbh = kb_ + (size_t)bh * T * D;
  const ushort* vbh = vtb_ + (size_t)bh * D * T;

  int qg0 = Q0 + wave * 16 + lrow;
  int qg1 = qg0 + 64;
  bf16x8 qf[2][2];
  {
    const ushort* qp0 = qb_ + ((size_t)bh * T + qg0) * D + quad * 8;
    qf[0][0] = *(const bf16x8*)qp0;
    qf[0][1] = *(const bf16x8*)(qp0 + 32);
    const ushort* qp1 = qb_ + ((size_t)bh * T + qg1) * D + quad * 8;
    qf[1][0] = *(const bf16x8*)qp1;
    qf[1][1] = *(const bf16x8*)(qp1 + 32);
  }
  int r7 = lrow & 7;
  int sw0 = (quad ^ r7) * 8;
  int sw1 = ((quad + 4) ^ r7) * 8;

  f32x4 o[4][2];
#pragma unroll
  for (int ds = 0; ds < 4; ds++)
#pragma unroll
    for (int g = 0; g < 2; g++) o[ds][g] = (f32x4){0.f, 0.f, 0.f, 0.f};
  f32x4 ol[2] = {(f32x4){0.f, 0.f, 0.f, 0.f}, (f32x4){0.f, 0.f, 0.f, 0.f}};

  int trips = 2 * qbi + 2;
  stage_kv(kbh, vbh, 0, Kl[0], Vl[0], tid);
  int it = 0;
  for (; it < trips - 2; ++it) {
    __syncthreads();
    stage_kv(kbh, vbh, (it + 1) * 64, Kl[(it + 1) & 1], Vl[(it + 1) & 1], tid);
    attn_step4<0>(it * 64, Kl[it & 1], Vl[it & 1], P, qf, lrow, quad, sw0, sw1,
                  qg0, qg1, o, ol);
  }
  __syncthreads();
  stage_kv(kbh, vbh, (it + 1) * 64, Kl[(it + 1) & 1], Vl[(it + 1) & 1], tid);
  attn_step4<1>(it * 64, Kl[it & 1], Vl[it & 1], P, qf, lrow, quad, sw0, sw1,
                qg0, qg1, o, ol);
  ++it;
  __syncthreads();
  attn_step4<2>(it * 64, Kl[it & 1], Vl[it & 1], P, qf, lrow, quad, sw0, sw1,
                qg0, qg1, o, ol);

#pragma unroll
  for (int g = 0; g < 2; g++) {
    float inv = 1.f / ol[g][0];
    int qg = g ? qg1 : qg0;
#pragma unroll
    for (int ds = 0; ds < 4; ds++) {
      ushort4 pk;
      pk.x = f2bf(o[ds][g][0] * inv);
      pk.y = f2bf(o[ds][g][1] * inv);
      pk.z = f2bf(o[ds][g][2] * inv);
      pk.w = f2bf(o[ds][g][3] * inv);
      *(ushort4*)(y + ((size_t)b * T + qg) * C + h * D + ds * 16 + quad * 4) = pk;
    }
  }
}

// ---------------------------------------------------------------------------
extern "C" void kernel_launch(void* const* d_in, const int* in_sizes, int n_in,
                              void* d_out, int out_size, void* d_ws, size_t ws_size,
                              hipStream_t stream) {
  const float* x  = (const float*)d_in[0];
  const float* wq = (const float*)d_in[1];
  const float* bq = (const float*)d_in[2];
  const float* wk = (const float*)d_in[3];
  const float* bk = (const float*)d_in[4];
  const float* wv = (const float*)d_in[5];
  const float* bv = (const float*)d_in[6];
  const float* wp = (const float*)d_in[7];
  const float* bp = (const float*)d_in[8];
  float* out = (float*)d_out;

  ushort* xb    = (ushort*)d_ws;            // (B,T,C)   bf16
  ushort* qb    = xb + BTC;                 // (B,H,T,D) bf16 (exp2-scaled)
  ushort* kb    = qb + BTC;                 // (B,H,T,D) bf16
  ushort* vtb   = kb + BTC;                 // (B,H,D,T) bf16
  ushort* yb    = vtb + BTC;                // (B,T,C)   bf16
  ushort* wqkvb = yb + BTC;                 // (3C,C) bf16, wpb after
  ushort* wpb   = wqkvb + (size_t)3 * C * C;

  f32_to_bf16<<<(int)(BTC / 1024), 256, 0, stream>>>(x, xb);
  conv_weights<<<4 * (C * C) / 1024, 256, 0, stream>>>(wq, wk, wv, wp, wqkvb);

  // fused QKV GEMM: 256^2 8-phase, RoPE + layout transforms in epilogue
  dim3 qkv_grid(3 * C / 256, M / 256);      // (12, 32) = 384 blocks
  gemm256_qkv<<<qkv_grid, 512, 0, stream>>>(
      xb, wqkvb, bq, bk, bv, qb, kb, vtb);

  attn_mfma4<<<(B * H * T / 128), 256, 0, stream>>>(qb, kb, vtb, yb);

  dim3 proj_grid(C / GT, M / GT);           // (8, 64)
  gemm_mfma_bt<0><<<proj_grid, 256, 0, stream>>>(
      yb, wpb, bp, bp, bp, out, nullptr, nullptr, C, C);
}

// Round 2
// 247.205 us; speedup vs baseline: 1.0212x; 1.0212x over previous
//
#include <hip/hip_runtime.h>
#include <math.h>

constexpr int B = 4, T = 2048, C = 1024, H = 16, D = 64;
constexpr int M = B * T;
constexpr size_t BTC = (size_t)B * T * C;
constexpr float QSCALE = 0.18033688011112042f;   // 0.125 * log2(e)
constexpr float ROPE_C = -0.415241011861f;       // -log2(10000)/32

typedef short bf16x8 __attribute__((ext_vector_type(8)));
typedef float f32x4 __attribute__((ext_vector_type(4)));

__device__ inline ushort f2bf(float f) {
  union { float f; unsigned u; } cv; cv.f = f;
  unsigned u = cv.u;
  u += 0x7fffu + ((u >> 16) & 1u);   // round-to-nearest-even
  return (ushort)(u >> 16);
}
__device__ inline ushort f2bfr(float f) {  // fast round (P only)
  union { float f; unsigned u; } cv; cv.f = f;
  return (ushort)((cv.u + 0x8000u) >> 16);
}

__device__ inline void async_load16(const void* g, void* l) {
  __builtin_amdgcn_global_load_lds(
      (const __attribute__((address_space(1))) void*)g,
      (__attribute__((address_space(3))) void*)l, 16, 0, 0);
}

__device__ __forceinline__ bf16x8 ones_frag() {
  bf16x8 v;
#pragma unroll
  for (int i = 0; i < 8; i++) v[i] = (short)0x3F80;  // bf16 1.0
  return v;
}

// ---------------------------------------------------------------------------
// fp32 -> bf16 conversion, 4 elems/thread
// ---------------------------------------------------------------------------
__global__ __launch_bounds__(256) void f32_to_bf16(
    const float* __restrict__ in, ushort* __restrict__ outp) {
  int i = (blockIdx.x * 256 + threadIdx.x) * 4;
  float4 v = *(const float4*)(in + i);
  ushort4 o;
  o.x = f2bf(v.x); o.y = f2bf(v.y); o.z = f2bf(v.z); o.w = f2bf(v.w);
  *(ushort4*)(outp + i) = o;
}

// Convert 4 weight matrices (C*C each) into contiguous dst in one launch.
__global__ __launch_bounds__(256) void conv_weights(
    const float* __restrict__ w0, const float* __restrict__ w1,
    const float* __restrict__ w2, const float* __restrict__ w3,
    ushort* __restrict__ outp) {
  const int seg_blocks = (C * C) / 1024;
  int seg = blockIdx.x / seg_blocks;
  int blk = blockIdx.x - seg * seg_blocks;
  const float* src = (seg == 0) ? w0 : (seg == 1) ? w1 : (seg == 2) ? w2 : w3;
  int i = (blk * 256 + threadIdx.x) * 4;
  float4 v = *(const float4*)(src + i);
  ushort4 o;
  o.x = f2bf(v.x); o.y = f2bf(v.y); o.z = f2bf(v.z); o.w = f2bf(v.w);
  *(ushort4*)(outp + (size_t)seg * C * C + i) = o;
}

// ---------------------------------------------------------------------------
// QKV GEMM: 256(M) x 128(N) tile, BK=64, 512 thr = 8 waves (4M x 2N grid),
// per-wave 64x64 output (identical fragments/epilogue to the proven 128^2
// kernel). Counted-vmcnt pipeline: A double-buffered (depth 1), B
// triple-buffered (depth 2); one s_waitcnt vmcnt(2) per K-tile so B(t+2)'s
// two loads always stay in flight across the tile boundary.
// Grid = 24 x 32 = 768 blocks = exactly 3 rounds of 256 CUs (no tail).
// LDS = 64 KiB (A dbuf) + 48 KiB (B 3-buf) = 112 KiB -> 1 block/CU.
// ---------------------------------------------------------------------------
constexpr int QNT = C / 64;  // 16 K-tiles

__global__ __launch_bounds__(512, 2) void gemm_qkv_256x128(
    const ushort* __restrict__ A, const ushort* __restrict__ Wt,
    const float* __restrict__ b0, const float* __restrict__ b1,
    const float* __restrict__ b2, ushort* __restrict__ outq,
    ushort* __restrict__ outk, ushort* __restrict__ outv) {
  __shared__ ushort As[2][256 * 64] __attribute__((aligned(16)));
  __shared__ ushort Bs[3][128 * 64] __attribute__((aligned(16)));
  const int tid = threadIdx.x;
  const int lane = tid & 63;
  const int lrow = lane & 15, quad = lane >> 4;
  const int wave = tid >> 6;
  const int wr = wave >> 1, wc = wave & 1;   // 4M x 2N wave grid
  const int x7 = lrow & 7;

  // XCD-aware bijective swizzle: 768 = 8 XCDs x 96 contiguous tiles.
  // Each XCD gets 4 row-panels x all 24 col-tiles -> A panel reuse in its L2.
  int bid = blockIdx.y * 24 + blockIdx.x;
  int lin = (bid & 7) * 96 + (bid >> 3);
  int row0 = (lin / 24) * 256;
  int col0 = (lin % 24) * 128;

  // Staging addresses: source col-chunk XOR-swizzled so linear
  // global_load_lds destinations give a swizzled LDS tile.
  unsigned gaA[4], gaB[2];
#pragma unroll
  for (int i = 0; i < 4; i++) {
    int c = tid + i * 512;
    int r = c >> 3, cl = c & 7;
    gaA[i] = (unsigned)(row0 + r) * C + (cl ^ (r & 7)) * 8;
  }
#pragma unroll
  for (int i = 0; i < 2; i++) {
    int c = tid + i * 512;
    int r = c >> 3, cl = c & 7;
    gaB[i] = (unsigned)(col0 + r) * C + (cl ^ (r & 7)) * 8;
  }

  f32x4 acc[4][4];
#pragma unroll
  for (int i = 0; i < 4; i++)
#pragma unroll
    for (int j = 0; j < 4; j++) acc[i][j] = (f32x4){0.f, 0.f, 0.f, 0.f};

  // ---- prologue: A(0),B(0),B(1); wait A(0)+B(0), leave B(1) in flight ----
#pragma unroll
  for (int i = 0; i < 4; i++)
    async_load16(A + gaA[i], &As[0][(tid + i * 512) * 8]);
#pragma unroll
  for (int i = 0; i < 2; i++)
    async_load16(Wt + gaB[i], &Bs[0][(tid + i * 512) * 8]);
#pragma unroll
  for (int i = 0; i < 2; i++)
    async_load16(Wt + gaB[i] + 64, &Bs[1][(tid + i * 512) * 8]);
  asm volatile("s_waitcnt vmcnt(2)" ::: "memory");
  __builtin_amdgcn_sched_barrier(0);
  __builtin_amdgcn_s_barrier();

  int bi = 0;  // t % 3
  for (int t = 0; t < QNT; ++t) {
    const int pa = t & 1;
    const ushort* Ap = As[pa];
    const ushort* Bp = Bs[bi];

    // ---- phase 0 (kh=0): 8 ds_reads; prefetch A(t+1) into As[pa^1] ----
    {
      const int slot = (quad ^ x7) * 8;
      bf16x8 af[4], bfr[4];
#pragma unroll
      for (int i = 0; i < 4; i++)
        af[i] = *(const bf16x8*)&Ap[(wr * 64 + i * 16 + lrow) * 64 + slot];
#pragma unroll
      for (int j = 0; j < 4; j++)
        bfr[j] = *(const bf16x8*)&Bp[(wc * 64 + j * 16 + lrow) * 64 + slot];
      if (t + 1 < QNT) {
#pragma unroll
        for (int i = 0; i < 4; i++)
          async_load16(A + gaA[i] + (t + 1) * 64,
                       &As[pa ^ 1][(tid + i * 512) * 8]);
      }
      __builtin_amdgcn_s_barrier();
      asm volatile("s_waitcnt lgkmcnt(0)" ::: "memory");
      __builtin_amdgcn_sched_barrier(0);
      __builtin_amdgcn_s_setprio(1);
#pragma unroll
      for (int i = 0; i < 4; i++)
#pragma unroll
        for (int j = 0; j < 4; j++)
          acc[i][j] = __builtin_amdgcn_mfma_f32_16x16x32_bf16(
              af[i], bfr[j], acc[i][j], 0, 0, 0);
      __builtin_amdgcn_s_setprio(0);
      __builtin_amdgcn_s_barrier();
    }

    // ---- phase 1 (kh=1): 8 ds_reads; prefetch B(t+2) into 3rd buffer ----
    {
      const int slot = ((4 + quad) ^ x7) * 8;
      bf16x8 af[4], bfr[4];
#pragma unroll
      for (int i = 0; i < 4; i++)
        af[i] = *(const bf16x8*)&Ap[(wr * 64 + i * 16 + lrow) * 64 + slot];
#pragma unroll
      for (int j = 0; j < 4; j++)
        bfr[j] = *(const bf16x8*)&Bp[(wc * 64 + j * 16 + lrow) * 64 + slot];
      if (t + 2 < QNT) {
        int bi2 = bi - 1; if (bi2 < 0) bi2 = 2;   // (bi+2) % 3
#pragma unroll
        for (int i = 0; i < 2; i++)
          async_load16(Wt + gaB[i] + (t + 2) * 64,
                       &Bs[bi2][(tid + i * 512) * 8]);
      }
      __builtin_amdgcn_s_barrier();
      asm volatile("s_waitcnt lgkmcnt(0)" ::: "memory");
      __builtin_amdgcn_sched_barrier(0);
      __builtin_amdgcn_s_setprio(1);
#pragma unroll
      for (int i = 0; i < 4; i++)
#pragma unroll
        for (int j = 0; j < 4; j++)
          acc[i][j] = __builtin_amdgcn_mfma_f32_16x16x32_bf16(
              af[i], bfr[j], acc[i][j], 0, 0, 0);
      __builtin_amdgcn_s_setprio(0);
      // counted wait: A(t+1)+B(t+1) complete, B(t+2) stays in flight
      if (t + 2 < QNT) {
        asm volatile("s_waitcnt vmcnt(2)" ::: "memory");
      } else {
        asm volatile("s_waitcnt vmcnt(0)" ::: "memory");
      }
      __builtin_amdgcn_sched_barrier(0);
      __builtin_amdgcn_s_barrier();
    }
    bi = (bi + 1 == 3) ? 0 : bi + 1;
  }

  // ---- fused epilogue (verbatim from the proven 128^2 kernel) ----
  const int nb = col0 + wc * 64;             // head-aligned (64 | nb)
  const int mbase = row0 + wr * 64;
  const float* bias = (col0 < 1024) ? b0 : (col0 < 2048) ? b1 : b2;
  float bn[4];
#pragma unroll
  for (int j = 0; j < 4; j++) bn[j] = bias[(nb & 1023) + j * 16 + lrow];

  int seg = nb >> 10;                        // 0=Q, 1=K, 2=V
  int hh = (nb & 1023) >> 6;                 // head index
  if (seg < 2) {
    // RoPE: lane holds d = lrow(+16) and d+32 -> both pair halves local.
    ushort* dst = (seg == 0) ? outq : outk;
    float scale = (seg == 0) ? QSCALE : 1.0f;
    float a0 = __builtin_amdgcn_exp2f((float)lrow * ROPE_C);
    float a1 = __builtin_amdgcn_exp2f((float)(lrow + 16) * ROPE_C);
#pragma unroll
    for (int i = 0; i < 4; i++) {
#pragma unroll
      for (int r = 0; r < 4; r++) {
        int m = mbase + i * 16 + quad * 4 + r;
        int tt = m & (T - 1), bb = m >> 11;
        float s0, c0, s1, c1;
        __sincosf((float)tt * a0, &s0, &c0);
        __sincosf((float)tt * a1, &s1, &c1);
        float xr0 = acc[i][0][r] + bn[0];
        float xi0 = acc[i][2][r] + bn[2];
        float xr1 = acc[i][1][r] + bn[1];
        float xi1 = acc[i][3][r] + bn[3];
        ushort* pp = dst + ((size_t)(bb * H + hh) * T + tt) * D + lrow;
        pp[0]  = f2bf((xr0 * c0 - xi0 * s0) * scale);
        pp[32] = f2bf((xr0 * s0 + xi0 * c0) * scale);
        pp[16] = f2bf((xr1 * c1 - xi1 * s1) * scale);
        pp[48] = f2bf((xr1 * s1 + xi1 * c1) * scale);
      }
    }
  } else {
    // V: write transposed (B,H,D,T); 4 consecutive t per quad -> ushort4
#pragma unroll
    for (int i = 0; i < 4; i++) {
      int m0 = mbase + i * 16 + quad * 4;
      int t0 = m0 & (T - 1), bb = m0 >> 11;
      size_t base = (size_t)(bb * H + hh) * D * T + t0;
#pragma unroll
      for (int j = 0; j < 4; j++) {
        int d = j * 16 + lrow;
        ushort4 pk;
        pk.x = f2bf(acc[i][j][0] + bn[j]);
        pk.y = f2bf(acc[i][j][1] + bn[j]);
        pk.z = f2bf(acc[i][j][2] + bn[j]);
        pk.w = f2bf(acc[i][j][3] + bn[j]);
        *(ushort4*)(outv + base + (size_t)d * T) = pk;
      }
    }
  }
}

// ---------------------------------------------------------------------------
// MFMA GEMM: 128x128 tile, BK=64 (kept for the proj GEMM, OM=0 only).
// ---------------------------------------------------------------------------
#define GT 128
#define GBK 64
template <int OM>
__global__ __launch_bounds__(256) void gemm_mfma_bt(
    const ushort* __restrict__ A, const ushort* __restrict__ Wt,
    const float* __restrict__ b0, const float* __restrict__ b1,
    const float* __restrict__ b2, void* __restrict__ out1,
    void* __restrict__ out2, void* __restrict__ out3,
    int N, int K) {
  __shared__ ushort As[GT * GBK] __attribute__((aligned(16)));
  __shared__ ushort Bs[GT * GBK] __attribute__((aligned(16)));
  int tid = threadIdx.x;
  int lane = tid & 63;
  int lrow = lane & 15, quad = lane >> 4;
  int wave = tid >> 6;
  int wr = wave >> 1, wc = wave & 1;
  int row0 = blockIdx.y * GT;
  int col0 = blockIdx.x * GT;
  const float* bias = (col0 < 1024) ? b0 : (col0 < 2048) ? b1 : b2;

  size_t ga[4], gb[4];
#pragma unroll
  for (int i = 0; i < 4; i++) {
    int cc = tid + i * 256;
    int r = cc >> 3, cl = cc & 7;
    int g = (cl ^ (r & 7)) * 8;        // XOR-swizzled source col-chunk
    ga[i] = (size_t)(row0 + r) * K + g;
    gb[i] = (size_t)(col0 + r) * K + g;
  }
  int x7 = lrow & 7;

  f32x4 acc[4][4];
#pragma unroll
  for (int i = 0; i < 4; i++)
#pragma unroll
    for (int j = 0; j < 4; j++) acc[i][j] = (f32x4){0.f, 0.f, 0.f, 0.f};

  for (int k0 = 0; k0 < K; k0 += GBK) {
#pragma unroll
    for (int i = 0; i < 4; i++) {
      int cc = tid + i * 256;
      async_load16(A + ga[i] + k0, &As[cc * 8]);
      async_load16(Wt + gb[i] + k0, &Bs[cc * 8]);
    }
    __syncthreads();
#pragma unroll
    for (int kh = 0; kh < 2; kh++) {
      int slot = ((kh * 4 + quad) ^ x7) * 8;
      bf16x8 af[4], bfr[4];
#pragma unroll
      for (int i = 0; i < 4; i++)
        af[i] = *(const bf16x8*)&As[(wr * 64 + i * 16 + lrow) * GBK + slot];
#pragma unroll
      for (int j = 0; j < 4; j++)
        bfr[j] = *(const bf16x8*)&Bs[(wc * 64 + j * 16 + lrow) * GBK + slot];
#pragma unroll
      for (int i = 0; i < 4; i++)
#pragma unroll
        for (int j = 0; j < 4; j++)
          acc[i][j] = __builtin_amdgcn_mfma_f32_16x16x32_bf16(af[i], bfr[j], acc[i][j], 0, 0, 0);
    }
    __syncthreads();
  }

  int nb = col0 + wc * 64;             // head-aligned (64 | nb)
  int mbase = row0 + wr * 64;
  float bn[4];
#pragma unroll
  for (int j = 0; j < 4; j++) bn[j] = bias[(nb & 1023) + j * 16 + lrow];

  if (OM == 0) {
    float* outp = (float*)out1;
#pragma unroll
    for (int i = 0; i < 4; i++)
#pragma unroll
      for (int j = 0; j < 4; j++) {
        int n = nb + j * 16 + lrow;
#pragma unroll
        for (int r = 0; r < 4; r++) {
          int m = mbase + i * 16 + quad * 4 + r;
          outp[(size_t)m * N + n] = acc[i][j][r] + bn[j];
        }
      }
  }
}

// ---------------------------------------------------------------------------
// MFMA flash attention v4 (unchanged).
// ---------------------------------------------------------------------------
__device__ __forceinline__ void stage_kv(
    const ushort* kbh, const ushort* vbh, int s0,
    ushort* Kl, ushort* Vl, int tid) {
#pragma unroll
  for (int i = 0; i < 2; i++) {
    int c = tid + i * 256;
    int r = c >> 3, cc = c & 7;
    int g = (cc ^ (r & 7)) * 8;
    async_load16(kbh + (size_t)(s0 + r) * D + g, Kl + c * 8);
    async_load16(vbh + (size_t)r * T + s0 + g, Vl + c * 8);
  }
}

template <int MODE>
__device__ __forceinline__ void attn_step4(
    int s0, const ushort* KL, const ushort* VL, ushort* P,
    const bf16x8 (&qf)[2][2], int lrow, int quad, int sw0, int sw1,
    int qg0, int qg1, f32x4 (&o)[4][2], f32x4 (&ol)[2]) {
  bf16x8 kf0[4], kf1[4];
#pragma unroll
  for (int kt = 0; kt < 4; kt++) {
    int base = (kt * 16 + lrow) * 64;
    kf0[kt] = *(const bf16x8*)&KL[base + sw0];
    kf1[kt] = *(const bf16x8*)&KL[base + sw1];
  }
  bf16x8 vf0[4], vf1[4];
#pragma unroll
  for (int ds = 0; ds < 4; ds++) {
    int base = (ds * 16 + lrow) * 64;
    vf0[ds] = *(const bf16x8*)&VL[base + sw0];
    vf1[ds] = *(const bf16x8*)&VL[base + sw1];
  }
#pragma unroll
  for (int g = 0; g < 2; g++) {
    if (MODE == 2 && g == 0) continue;
    int qg = g ? qg1 : qg0;
    f32x4 st[4];
#pragma unroll
    for (int kt = 0; kt < 4; kt++) {
      f32x4 z = {0.f, 0.f, 0.f, 0.f};
      st[kt] = __builtin_amdgcn_mfma_f32_16x16x32_bf16(kf0[kt], qf[g][0], z, 0, 0, 0);
      st[kt] = __builtin_amdgcn_mfma_f32_16x16x32_bf16(kf1[kt], qf[g][1], st[kt], 0, 0, 0);
    }
    if ((MODE == 1 && g == 0) || (MODE == 2 && g == 1)) {
#pragma unroll
      for (int kt = 0; kt < 4; kt++)
#pragma unroll
        for (int r = 0; r < 4; r++)
          if (s0 + kt * 16 + quad * 4 + r > qg) st[kt][r] = -1e30f;
    }
#pragma unroll
    for (int kt = 0; kt < 4; kt++) {
      ushort4 pk;
      pk.x = f2bfr(__builtin_amdgcn_exp2f(st[kt][0]));
      pk.y = f2bfr(__builtin_amdgcn_exp2f(st[kt][1]));
      pk.z = f2bfr(__builtin_amdgcn_exp2f(st[kt][2]));
      pk.w = f2bfr(__builtin_amdgcn_exp2f(st[kt][3]));
      *(ushort4*)&P[((2 * kt + (quad >> 1)) * 32 + g * 16 + lrow) * 8 + (quad & 1) * 4] = pk;
    }
  }
  asm volatile("" ::: "memory");
  bf16x8 ones = ones_frag();
#pragma unroll
  for (int g = 0; g < 2; g++) {
    if (MODE == 2 && g == 0) continue;
    bf16x8 pf0 = *(const bf16x8*)&P[(quad * 32 + g * 16 + lrow) * 8];
    bf16x8 pf1 = *(const bf16x8*)&P[((quad + 4) * 32 + g * 16 + lrow) * 8];
    ol[g] = __builtin_amdgcn_mfma_f32_16x16x32_bf16(ones, pf0, ol[g], 0, 0, 0);
    ol[g] = __builtin_amdgcn_mfma_f32_16x16x32_bf16(ones, pf1, ol[g], 0, 0, 0);
#pragma unroll
    for (int ds = 0; ds < 4; ds++) {
      o[ds][g] = __builtin_amdgcn_mfma_f32_16x16x32_bf16(vf0[ds], pf0, o[ds][g], 0, 0, 0);
      o[ds][g] = __builtin_amdgcn_mfma_f32_16x16x32_bf16(vf1[ds], pf1, o[ds][g], 0, 0, 0);
    }
  }
}

__global__ __launch_bounds__(256, 3) void attn_mfma4(
    const ushort* __restrict__ qb_, const ushort* __restrict__ kb_,
    const ushort* __restrict__ vtb_, ushort* __restrict__ y) {
  __shared__ ushort Kl[2][64 * 64] __attribute__((aligned(16)));
  __shared__ ushort Vl[2][64 * 64] __attribute__((aligned(16)));
  __shared__ ushort Pl[4][2048] __attribute__((aligned(16)));
  int tid = threadIdx.x;
  int wave = tid >> 6, lane = tid & 63;
  int lrow = lane & 15, quad = lane >> 4;
  int qbi = 15 - (int)(blockIdx.x >> 6);
  int bh = blockIdx.x & 63;
  int b = bh >> 4, h = bh & 15;
  int Q0 = qbi * 128;
  ushort* P = Pl[wave];
  const ushort* kbh = kb_ + (size_t)bh * T * D;
  const ushort* vbh = vtb_ + (size_t)bh * D * T;

  int qg0 = Q0 + wave * 16 + lrow;
  int qg1 = qg0 + 64;
  bf16x8 qf[2][2];
  {
    const ushort* qp0 = qb_ + ((size_t)bh * T + qg0) * D + quad * 8;
    qf[0][0] = *(const bf16x8*)qp0;
    qf[0][1] = *(const bf16x8*)(qp0 + 32);
    const ushort* qp1 = qb_ + ((size_t)bh * T + qg1) * D + quad * 8;
    qf[1][0] = *(const bf16x8*)qp1;
    qf[1][1] = *(const bf16x8*)(qp1 + 32);
  }
  int r7 = lrow & 7;
  int sw0 = (quad ^ r7) * 8;
  int sw1 = ((quad + 4) ^ r7) * 8;

  f32x4 o[4][2];
#pragma unroll
  for (int ds = 0; ds < 4; ds++)
#pragma unroll
    for (int g = 0; g < 2; g++) o[ds][g] = (f32x4){0.f, 0.f, 0.f, 0.f};
  f32x4 ol[2] = {(f32x4){0.f, 0.f, 0.f, 0.f}, (f32x4){0.f, 0.f, 0.f, 0.f}};

  int trips = 2 * qbi + 2;
  stage_kv(kbh, vbh, 0, Kl[0], Vl[0], tid);
  int it = 0;
  for (; it < trips - 2; ++it) {
    __syncthreads();
    stage_kv(kbh, vbh, (it + 1) * 64, Kl[(it + 1) & 1], Vl[(it + 1) & 1], tid);
    attn_step4<0>(it * 64, Kl[it & 1], Vl[it & 1], P, qf, lrow, quad, sw0, sw1,
                  qg0, qg1, o, ol);
  }
  __syncthreads();
  stage_kv(kbh, vbh, (it + 1) * 64, Kl[(it + 1) & 1], Vl[(it + 1) & 1], tid);
  attn_step4<1>(it * 64, Kl[it & 1], Vl[it & 1], P, qf, lrow, quad, sw0, sw1,
                qg0, qg1, o, ol);
  ++it;
  __syncthreads();
  attn_step4<2>(it * 64, Kl[it & 1], Vl[it & 1], P, qf, lrow, quad, sw0, sw1,
                qg0, qg1, o, ol);

#pragma unroll
  for (int g = 0; g < 2; g++) {
    float inv = 1.f / ol[g][0];
    int qg = g ? qg1 : qg0;
#pragma unroll
    for (int ds = 0; ds < 4; ds++) {
      ushort4 pk;
      pk.x = f2bf(o[ds][g][0] * inv);
      pk.y = f2bf(o[ds][g][1] * inv);
      pk.z = f2bf(o[ds][g][2] * inv);
      pk.w = f2bf(o[ds][g][3] * inv);
      *(ushort4*)(y + ((size_t)b * T + qg) * C + h * D + ds * 16 + quad * 4) = pk;
    }
  }
}

// ---------------------------------------------------------------------------
extern "C" void kernel_launch(void* const* d_in, const int* in_sizes, int n_in,
                              void* d_out, int out_size, void* d_ws, size_t ws_size,
                              hipStream_t stream) {
  const float* x  = (const float*)d_in[0];
  const float* wq = (const float*)d_in[1];
  const float* bq = (const float*)d_in[2];
  const float* wk = (const float*)d_in[3];
  const float* bk = (const float*)d_in[4];
  const float* wv = (const float*)d_in[5];
  const float* bv = (const float*)d_in[6];
  const float* wp = (const float*)d_in[7];
  const float* bp = (const float*)d_in[8];
  float* out = (float*)d_out;

  ushort* xb    = (ushort*)d_ws;            // (B,T,C)   bf16
  ushort* qb    = xb + BTC;                 // (B,H,T,D) bf16 (exp2-scaled)
  ushort* kb    = qb + BTC;                 // (B,H,T,D) bf16
  ushort* vtb   = kb + BTC;                 // (B,H,D,T) bf16
  ushort* yb    = vtb + BTC;                // (B,T,C)   bf16
  ushort* wqkvb = yb + BTC;                 // (3C,C) bf16, wpb after
  ushort* wpb   = wqkvb + (size_t)3 * C * C;

  f32_to_bf16<<<(int)(BTC / 1024), 256, 0, stream>>>(x, xb);
  conv_weights<<<4 * (C * C) / 1024, 256, 0, stream>>>(wq, wk, wv, wp, wqkvb);

  // fused QKV GEMM: 256x128 counted-vmcnt pipeline, RoPE + layout in epilogue
  dim3 qkv_grid(3 * C / 128, M / 256);      // (24, 32) = 768 blocks, 3 rounds
  gemm_qkv_256x128<<<qkv_grid, 512, 0, stream>>>(
      xb, wqkvb, bq, bk, bv, qb, kb, vtb);

  attn_mfma4<<<(B * H * T / 128), 256, 0, stream>>>(qb, kb, vtb, yb);

  dim3 proj_grid(C / GT, M / GT);           // (8, 64)
  gemm_mfma_bt<0><<<proj_grid, 256, 0, stream>>>(
      yb, wpb, bp, bp, bp, out, nullptr, nullptr, C, C);
}

// Round 3
// 231.483 us; speedup vs baseline: 1.0905x; 1.0679x over previous
//
#include <hip/hip_runtime.h>
#include <math.h>

constexpr int B = 4, T = 2048, C = 1024, H = 16, D = 64;
constexpr int M = B * T;
constexpr size_t BTC = (size_t)B * T * C;
constexpr float QSCALE = 0.18033688011112042f;   // 0.125 * log2(e)
constexpr float ROPE_C = -0.415241011861f;       // -log2(10000)/32

typedef short bf16x8 __attribute__((ext_vector_type(8)));
typedef float f32x4 __attribute__((ext_vector_type(4)));

__device__ inline ushort f2bf(float f) {
  union { float f; unsigned u; } cv; cv.f = f;
  unsigned u = cv.u;
  u += 0x7fffu + ((u >> 16) & 1u);   // round-to-nearest-even
  return (ushort)(u >> 16);
}
__device__ inline ushort f2bfr(float f) {  // fast round (P only)
  union { float f; unsigned u; } cv; cv.f = f;
  return (ushort)((cv.u + 0x8000u) >> 16);
}

__device__ inline void async_load16(const void* g, void* l) {
  __builtin_amdgcn_global_load_lds(
      (const __attribute__((address_space(1))) void*)g,
      (__attribute__((address_space(3))) void*)l, 16, 0, 0);
}

__device__ __forceinline__ bf16x8 ones_frag() {
  bf16x8 v;
#pragma unroll
  for (int i = 0; i < 8; i++) v[i] = (short)0x3F80;  // bf16 1.0
  return v;
}

// ---------------------------------------------------------------------------
// fp32 -> bf16 conversion, 4 elems/thread
// ---------------------------------------------------------------------------
__global__ __launch_bounds__(256) void f32_to_bf16(
    const float* __restrict__ in, ushort* __restrict__ outp) {
  int i = (blockIdx.x * 256 + threadIdx.x) * 4;
  float4 v = *(const float4*)(in + i);
  ushort4 o;
  o.x = f2bf(v.x); o.y = f2bf(v.y); o.z = f2bf(v.z); o.w = f2bf(v.w);
  *(ushort4*)(outp + i) = o;
}

// Convert 4 weight matrices (C*C each) into contiguous dst in one launch.
__global__ __launch_bounds__(256) void conv_weights(
    const float* __restrict__ w0, const float* __restrict__ w1,
    const float* __restrict__ w2, const float* __restrict__ w3,
    ushort* __restrict__ outp) {
  const int seg_blocks = (C * C) / 1024;
  int seg = blockIdx.x / seg_blocks;
  int blk = blockIdx.x - seg * seg_blocks;
  const float* src = (seg == 0) ? w0 : (seg == 1) ? w1 : (seg == 2) ? w2 : w3;
  int i = (blk * 256 + threadIdx.x) * 4;
  float4 v = *(const float4*)(src + i);
  ushort4 o;
  o.x = f2bf(v.x); o.y = f2bf(v.y); o.z = f2bf(v.z); o.w = f2bf(v.w);
  *(ushort4*)(outp + (size_t)seg * C * C + i) = o;
}

// ---------------------------------------------------------------------------
// Pipelined GEMM: 256(M) x 128(N) tile, BK=64, 512 thr = 8 waves (4M x 2N),
// per-wave 64x64 output. ONE barrier per K-tile: reads + stage-issues + MFMA
// free-flow within the tile (compiler emits partial lgkmcnt interleave; the
// 2 waves/SIMD desynchronize so LDS reads overlap MFMA). Counted
// s_waitcnt vmcnt(2) per tile keeps B(t+2)'s loads in flight across the
// barrier (never drains to 0 in steady state).
// A double-buffered, B triple-buffered. LDS = 64+48 = 112 KiB -> 1 block/CU.
// OM=1: fused QKV epilogue (RoPE + V-transpose). OM=0: fp32 out + bias.
// Grid = NCT x 32 blocks; NCT=24 (qkv, 768 = 3 exact rounds) or
// NCT=8 (proj, 256 = 1 exact round). XCD-bijective block swizzle.
// ---------------------------------------------------------------------------
constexpr int QNT = C / 64;  // 16 K-tiles

template <int OM, int NCT>
__global__ __launch_bounds__(512, 2) void gemm_pipe(
    const ushort* __restrict__ A, const ushort* __restrict__ Wt,
    const float* __restrict__ b0, const float* __restrict__ b1,
    const float* __restrict__ b2, void* __restrict__ out1,
    void* __restrict__ out2, void* __restrict__ out3) {
  __shared__ ushort As[2][256 * 64] __attribute__((aligned(16)));
  __shared__ ushort Bs[3][128 * 64] __attribute__((aligned(16)));
  const int tid = threadIdx.x;
  const int lane = tid & 63;
  const int lrow = lane & 15, quad = lane >> 4;
  const int wave = tid >> 6;
  const int wr = wave >> 1, wc = wave & 1;   // 4M x 2N wave grid
  const int x7 = lrow & 7;

  // XCD-aware bijective swizzle: grid = NCT x 32, NCT*32 % 8 == 0.
  int bid = blockIdx.y * NCT + blockIdx.x;
  const int cpx = NCT * 4;                   // blocks per XCD
  int lin = (bid & 7) * cpx + (bid >> 3);
  int row0 = (lin / NCT) * 256;
  int col0 = (lin % NCT) * 128;

  // Staging addresses: source col-chunk XOR-swizzled so linear
  // global_load_lds destinations give a swizzled LDS tile.
  unsigned gaA[4], gaB[2];
#pragma unroll
  for (int i = 0; i < 4; i++) {
    int c = tid + i * 512;
    int r = c >> 3, cl = c & 7;
    gaA[i] = (unsigned)(row0 + r) * C + (cl ^ (r & 7)) * 8;
  }
#pragma unroll
  for (int i = 0; i < 2; i++) {
    int c = tid + i * 512;
    int r = c >> 3, cl = c & 7;
    gaB[i] = (unsigned)(col0 + r) * C + (cl ^ (r & 7)) * 8;
  }

  f32x4 acc[4][4];
#pragma unroll
  for (int i = 0; i < 4; i++)
#pragma unroll
    for (int j = 0; j < 4; j++) acc[i][j] = (f32x4){0.f, 0.f, 0.f, 0.f};

  // ---- prologue: A(0),B(0),B(1); wait A(0)+B(0), leave B(1) in flight ----
#pragma unroll
  for (int i = 0; i < 4; i++)
    async_load16(A + gaA[i], &As[0][(tid + i * 512) * 8]);
#pragma unroll
  for (int i = 0; i < 2; i++)
    async_load16(Wt + gaB[i], &Bs[0][(tid + i * 512) * 8]);
#pragma unroll
  for (int i = 0; i < 2; i++)
    async_load16(Wt + gaB[i] + 64, &Bs[1][(tid + i * 512) * 8]);
  asm volatile("s_waitcnt vmcnt(2)" ::: "memory");
  __builtin_amdgcn_sched_barrier(0);
  __builtin_amdgcn_s_barrier();

  int bi = 0;  // t % 3
  for (int t = 0; t < QNT; ++t) {
    const int pa = t & 1;
    const ushort* Ap = As[pa];
    const ushort* Bp = Bs[bi];
    int bi2 = bi - 1; if (bi2 < 0) bi2 = 2;  // (bi+2) % 3

    // ---- half 0 (kh=0): reads + A(t+1) prefetch + MFMA, no barrier ----
    {
      const int slot = (quad ^ x7) * 8;
      bf16x8 aF[4], bF[4];
#pragma unroll
      for (int i = 0; i < 4; i++)
        aF[i] = *(const bf16x8*)&Ap[(wr * 64 + i * 16 + lrow) * 64 + slot];
#pragma unroll
      for (int j = 0; j < 4; j++)
        bF[j] = *(const bf16x8*)&Bp[(wc * 64 + j * 16 + lrow) * 64 + slot];
      if (t + 1 < QNT) {
#pragma unroll
        for (int i = 0; i < 4; i++)
          async_load16(A + gaA[i] + (t + 1) * 64,
                       &As[pa ^ 1][(tid + i * 512) * 8]);
      }
      __builtin_amdgcn_s_setprio(1);
#pragma unroll
      for (int i = 0; i < 4; i++)
#pragma unroll
        for (int j = 0; j < 4; j++)
          acc[i][j] = __builtin_amdgcn_mfma_f32_16x16x32_bf16(
              aF[i], bF[j], acc[i][j], 0, 0, 0);
      __builtin_amdgcn_s_setprio(0);
    }

    // ---- half 1 (kh=1): reads + B(t+2) prefetch + MFMA ----
    {
      const int slot = ((4 + quad) ^ x7) * 8;
      bf16x8 aF[4], bF[4];
#pragma unroll
      for (int i = 0; i < 4; i++)
        aF[i] = *(const bf16x8*)&Ap[(wr * 64 + i * 16 + lrow) * 64 + slot];
#pragma unroll
      for (int j = 0; j < 4; j++)
        bF[j] = *(const bf16x8*)&Bp[(wc * 64 + j * 16 + lrow) * 64 + slot];
      if (t + 2 < QNT) {
#pragma unroll
        for (int i = 0; i < 2; i++)
          async_load16(Wt + gaB[i] + (t + 2) * 64,
                       &Bs[bi2][(tid + i * 512) * 8]);
      }
      __builtin_amdgcn_s_setprio(1);
#pragma unroll
      for (int i = 0; i < 4; i++)
#pragma unroll
        for (int j = 0; j < 4; j++)
          acc[i][j] = __builtin_amdgcn_mfma_f32_16x16x32_bf16(
              aF[i], bF[j], acc[i][j], 0, 0, 0);
      __builtin_amdgcn_s_setprio(0);
    }

    // ---- single per-tile sync: counted wait, B(t+2) stays in flight ----
    if (t + 2 < QNT) {
      asm volatile("s_waitcnt vmcnt(2)" ::: "memory");
    } else {
      asm volatile("s_waitcnt vmcnt(0)" ::: "memory");
    }
    __builtin_amdgcn_sched_barrier(0);
    __builtin_amdgcn_s_barrier();
    bi = (bi == 2) ? 0 : bi + 1;
  }

  // ---- epilogue ----
  const int nb = col0 + wc * 64;             // head-aligned (64 | nb)
  const int mbase = row0 + wr * 64;
  const float* bias = (col0 < 1024) ? b0 : (col0 < 2048) ? b1 : b2;
  float bn[4];
#pragma unroll
  for (int j = 0; j < 4; j++) bn[j] = bias[(nb & 1023) + j * 16 + lrow];

  if (OM == 0) {
    const int N = NCT * 128;
    float* outp = (float*)out1;
#pragma unroll
    for (int i = 0; i < 4; i++)
#pragma unroll
      for (int j = 0; j < 4; j++) {
        int n = nb + j * 16 + lrow;
#pragma unroll
        for (int r = 0; r < 4; r++) {
          int m = mbase + i * 16 + quad * 4 + r;
          outp[(size_t)m * N + n] = acc[i][j][r] + bn[j];
        }
      }
  } else {
    int seg = nb >> 10;                      // 0=Q, 1=K, 2=V
    int hh = (nb & 1023) >> 6;               // head index
    if (seg < 2) {
      // RoPE: lane holds d = lrow(+16) and d+32 -> both pair halves local.
      ushort* dst = (seg == 0) ? (ushort*)out1 : (ushort*)out2;
      float scale = (seg == 0) ? QSCALE : 1.0f;
      float a0 = __builtin_amdgcn_exp2f((float)lrow * ROPE_C);
      float a1 = __builtin_amdgcn_exp2f((float)(lrow + 16) * ROPE_C);
#pragma unroll
      for (int i = 0; i < 4; i++) {
#pragma unroll
        for (int r = 0; r < 4; r++) {
          int m = mbase + i * 16 + quad * 4 + r;
          int tt = m & (T - 1), bb = m >> 11;
          float s0, c0, s1, c1;
          __sincosf((float)tt * a0, &s0, &c0);
          __sincosf((float)tt * a1, &s1, &c1);
          float xr0 = acc[i][0][r] + bn[0];
          float xi0 = acc[i][2][r] + bn[2];
          float xr1 = acc[i][1][r] + bn[1];
          float xi1 = acc[i][3][r] + bn[3];
          ushort* pp = dst + ((size_t)(bb * H + hh) * T + tt) * D + lrow;
          pp[0]  = f2bf((xr0 * c0 - xi0 * s0) * scale);
          pp[32] = f2bf((xr0 * s0 + xi0 * c0) * scale);
          pp[16] = f2bf((xr1 * c1 - xi1 * s1) * scale);
          pp[48] = f2bf((xr1 * s1 + xi1 * c1) * scale);
        }
      }
    } else {
      // V: write transposed (B,H,D,T); 4 consecutive t per quad -> ushort4
      ushort* dst = (ushort*)out3;
#pragma unroll
      for (int i = 0; i < 4; i++) {
        int m0 = mbase + i * 16 + quad * 4;
        int t0 = m0 & (T - 1), bb = m0 >> 11;
        size_t base = (size_t)(bb * H + hh) * D * T + t0;
#pragma unroll
        for (int j = 0; j < 4; j++) {
          int d = j * 16 + lrow;
          ushort4 pk;
          pk.x = f2bf(acc[i][j][0] + bn[j]);
          pk.y = f2bf(acc[i][j][1] + bn[j]);
          pk.z = f2bf(acc[i][j][2] + bn[j]);
          pk.w = f2bf(acc[i][j][3] + bn[j]);
          *(ushort4*)(dst + base + (size_t)d * T) = pk;
        }
      }
    }
  }
}

// ---------------------------------------------------------------------------
// MFMA flash attention v4 (unchanged).
// ---------------------------------------------------------------------------
__device__ __forceinline__ void stage_kv(
    const ushort* kbh, const ushort* vbh, int s0,
    ushort* Kl, ushort* Vl, int tid) {
#pragma unroll
  for (int i = 0; i < 2; i++) {
    int c = tid + i * 256;
    int r = c >> 3, cc = c & 7;
    int g = (cc ^ (r & 7)) * 8;
    async_load16(kbh + (size_t)(s0 + r) * D + g, Kl + c * 8);
    async_load16(vbh + (size_t)r * T + s0 + g, Vl + c * 8);
  }
}

template <int MODE>
__device__ __forceinline__ void attn_step4(
    int s0, const ushort* KL, const ushort* VL, ushort* P,
    const bf16x8 (&qf)[2][2], int lrow, int quad, int sw0, int sw1,
    int qg0, int qg1, f32x4 (&o)[4][2], f32x4 (&ol)[2]) {
  bf16x8 kf0[4], kf1[4];
#pragma unroll
  for (int kt = 0; kt < 4; kt++) {
    int base = (kt * 16 + lrow) * 64;
    kf0[kt] = *(const bf16x8*)&KL[base + sw0];
    kf1[kt] = *(const bf16x8*)&KL[base + sw1];
  }
  bf16x8 vf0[4], vf1[4];
#pragma unroll
  for (int ds = 0; ds < 4; ds++) {
    int base = (ds * 16 + lrow) * 64;
    vf0[ds] = *(const bf16x8*)&VL[base + sw0];
    vf1[ds] = *(const bf16x8*)&VL[base + sw1];
  }
#pragma unroll
  for (int g = 0; g < 2; g++) {
    if (MODE == 2 && g == 0) continue;
    int qg = g ? qg1 : qg0;
    f32x4 st[4];
#pragma unroll
    for (int kt = 0; kt < 4; kt++) {
      f32x4 z = {0.f, 0.f, 0.f, 0.f};
      st[kt] = __builtin_amdgcn_mfma_f32_16x16x32_bf16(kf0[kt], qf[g][0], z, 0, 0, 0);
      st[kt] = __builtin_amdgcn_mfma_f32_16x16x32_bf16(kf1[kt], qf[g][1], st[kt], 0, 0, 0);
    }
    if ((MODE == 1 && g == 0) || (MODE == 2 && g == 1)) {
#pragma unroll
      for (int kt = 0; kt < 4; kt++)
#pragma unroll
        for (int r = 0; r < 4; r++)
          if (s0 + kt * 16 + quad * 4 + r > qg) st[kt][r] = -1e30f;
    }
#pragma unroll
    for (int kt = 0; kt < 4; kt++) {
      ushort4 pk;
      pk.x = f2bfr(__builtin_amdgcn_exp2f(st[kt][0]));
      pk.y = f2bfr(__builtin_amdgcn_exp2f(st[kt][1]));
      pk.z = f2bfr(__builtin_amdgcn_exp2f(st[kt][2]));
      pk.w = f2bfr(__builtin_amdgcn_exp2f(st[kt][3]));
      *(ushort4*)&P[((2 * kt + (quad >> 1)) * 32 + g * 16 + lrow) * 8 + (quad & 1) * 4] = pk;
    }
  }
  asm volatile("" ::: "memory");
  bf16x8 ones = ones_frag();
#pragma unroll
  for (int g = 0; g < 2; g++) {
    if (MODE == 2 && g == 0) continue;
    bf16x8 pf0 = *(const bf16x8*)&P[(quad * 32 + g * 16 + lrow) * 8];
    bf16x8 pf1 = *(const bf16x8*)&P[((quad + 4) * 32 + g * 16 + lrow) * 8];
    ol[g] = __builtin_amdgcn_mfma_f32_16x16x32_bf16(ones, pf0, ol[g], 0, 0, 0);
    ol[g] = __builtin_amdgcn_mfma_f32_16x16x32_bf16(ones, pf1, ol[g], 0, 0, 0);
#pragma unroll
    for (int ds = 0; ds < 4; ds++) {
      o[ds][g] = __builtin_amdgcn_mfma_f32_16x16x32_bf16(vf0[ds], pf0, o[ds][g], 0, 0, 0);
      o[ds][g] = __builtin_amdgcn_mfma_f32_16x16x32_bf16(vf1[ds], pf1, o[ds][g], 0, 0, 0);
    }
  }
}

__global__ __launch_bounds__(256, 3) void attn_mfma4(
    const ushort* __restrict__ qb_, const ushort* __restrict__ kb_,
    const ushort* __restrict__ vtb_, ushort* __restrict__ y) {
  __shared__ ushort Kl[2][64 * 64] __attribute__((aligned(16)));
  __shared__ ushort Vl[2][64 * 64] __attribute__((aligned(16)));
  __shared__ ushort Pl[4][2048] __attribute__((aligned(16)));
  int tid = threadIdx.x;
  int wave = tid >> 6, lane = tid & 63;
  int lrow = lane & 15, quad = lane >> 4;
  int qbi = 15 - (int)(blockIdx.x >> 6);
  int bh = blockIdx.x & 63;
  int b = bh >> 4, h = bh & 15;
  int Q0 = qbi * 128;
  ushort* P = Pl[wave];
  const ushort* kbh = kb_ + (size_t)bh * T * D;
  const ushort* vbh = vtb_ + (size_t)bh * D * T;

  int qg0 = Q0 + wave * 16 + lrow;
  int qg1 = qg0 + 64;
  bf16x8 qf[2][2];
  {
    const ushort* qp0 = qb_ + ((size_t)bh * T + qg0) * D + quad * 8;
    qf[0][0] = *(const bf16x8*)qp0;
    qf[0][1] = *(const bf16x8*)(qp0 + 32);
    const ushort* qp1 = qb_ + ((size_t)bh * T + qg1) * D + quad * 8;
    qf[1][0] = *(const bf16x8*)qp1;
    qf[1][1] = *(const bf16x8*)(qp1 + 32);
  }
  int r7 = lrow & 7;
  int sw0 = (quad ^ r7) * 8;
  int sw1 = ((quad + 4) ^ r7) * 8;

  f32x4 o[4][2];
#pragma unroll
  for (int ds = 0; ds < 4; ds++)
#pragma unroll
    for (int g = 0; g < 2; g++) o[ds][g] = (f32x4){0.f, 0.f, 0.f, 0.f};
  f32x4 ol[2] = {(f32x4){0.f, 0.f, 0.f, 0.f}, (f32x4){0.f, 0.f, 0.f, 0.f}};

  int trips = 2 * qbi + 2;
  stage_kv(kbh, vbh, 0, Kl[0], Vl[0], tid);
  int it = 0;
  for (; it < trips - 2; ++it) {
    __syncthreads();
    stage_kv(kbh, vbh, (it + 1) * 64, Kl[(it + 1) & 1], Vl[(it + 1) & 1], tid);
    attn_step4<0>(it * 64, Kl[it & 1], Vl[it & 1], P, qf, lrow, quad, sw0, sw1,
                  qg0, qg1, o, ol);
  }
  __syncthreads();
  stage_kv(kbh, vbh, (it + 1) * 64, Kl[(it + 1) & 1], Vl[(it + 1) & 1], tid);
  attn_step4<1>(it * 64, Kl[it & 1], Vl[it & 1], P, qf, lrow, quad, sw0, sw1,
                qg0, qg1, o, ol);
  ++it;
  __syncthreads();
  attn_step4<2>(it * 64, Kl[it & 1], Vl[it & 1], P, qf, lrow, quad, sw0, sw1,
                qg0, qg1, o, ol);

#pragma unroll
  for (int g = 0; g < 2; g++) {
    float inv = 1.f / ol[g][0];
    int qg = g ? qg1 : qg0;
#pragma unroll
    for (int ds = 0; ds < 4; ds++) {
      ushort4 pk;
      pk.x = f2bf(o[ds][g][0] * inv);
      pk.y = f2bf(o[ds][g][1] * inv);
      pk.z = f2bf(o[ds][g][2] * inv);
      pk.w = f2bf(o[ds][g][3] * inv);
      *(ushort4*)(y + ((size_t)b * T + qg) * C + h * D + ds * 16 + quad * 4) = pk;
    }
  }
}

// ---------------------------------------------------------------------------
extern "C" void kernel_launch(void* const* d_in, const int* in_sizes, int n_in,
                              void* d_out, int out_size, void* d_ws, size_t ws_size,
                              hipStream_t stream) {
  const float* x  = (const float*)d_in[0];
  const float* wq = (const float*)d_in[1];
  const float* bq = (const float*)d_in[2];
  const float* wk = (const float*)d_in[3];
  const float* bk = (const float*)d_in[4];
  const float* wv = (const float*)d_in[5];
  const float* bv = (const float*)d_in[6];
  const float* wp = (const float*)d_in[7];
  const float* bp = (const float*)d_in[8];
  float* out = (float*)d_out;

  ushort* xb    = (ushort*)d_ws;            // (B,T,C)   bf16
  ushort* qb    = xb + BTC;                 // (B,H,T,D) bf16 (exp2-scaled)
  ushort* kb    = qb + BTC;                 // (B,H,T,D) bf16
  ushort* vtb   = kb + BTC;                 // (B,H,D,T) bf16
  ushort* yb    = vtb + BTC;                // (B,T,C)   bf16
  ushort* wqkvb = yb + BTC;                 // (3C,C) bf16, wpb after
  ushort* wpb   = wqkvb + (size_t)3 * C * C;

  f32_to_bf16<<<(int)(BTC / 1024), 256, 0, stream>>>(x, xb);
  conv_weights<<<4 * (C * C) / 1024, 256, 0, stream>>>(wq, wk, wv, wp, wqkvb);

  // fused QKV GEMM: single-barrier counted-vmcnt pipeline, 768 blocks (3 rounds)
  dim3 qkv_grid(3 * C / 128, M / 256);      // (24, 32)
  gemm_pipe<1, 24><<<qkv_grid, 512, 0, stream>>>(
      xb, wqkvb, bq, bk, bv, qb, kb, vtb);

  attn_mfma4<<<(B * H * T / 128), 256, 0, stream>>>(qb, kb, vtb, yb);

  // proj GEMM on the same pipeline, 256 blocks (1 exact round)
  dim3 proj_grid(C / 128, M / 256);         // (8, 32)
  gemm_pipe<0, 8><<<proj_grid, 512, 0, stream>>>(
      yb, wpb, bp, bp, bp, out, nullptr, nullptr);
}